// Round 9
// baseline (298.022 us; speedup 1.0000x reference)
//
#include <hip/hip_runtime.h>
#include <math.h>

// EdgeConv: B=16, N=8192, K=20, D=64 — two kernels + dynamic XCD-affine gather scheduling.
// Y1[p][o] = sum_d x[p][d]*W[o][d]                (bf16 table, gathered, L2-resident per XCD)
// Bs[p][o] = sum_d x[p][d]*(W[o][64+d]-W[o][d])   (bf16, streamed)
// out = GELU(LN(max_k Y1[idx_k] + Bs))
#define B_ 16
#define N_ 8192
#define K_ 20
#define NPTS (B_ * N_)   // 131072
#define NTILE 4096       // gather tiles (32 points each)
#define TPG 512          // tiles per XCD group (2 batches)

typedef __attribute__((ext_vector_type(4))) float f4;
typedef __attribute__((ext_vector_type(8))) short s8;           // 8 x bf16 MFMA fragment
typedef __attribute__((ext_vector_type(4))) unsigned int u4;    // 16B untyped
typedef __attribute__((ext_vector_type(4))) unsigned short us4; // 8B packed bf16

__device__ __forceinline__ unsigned short f2bf(float f) {
    union { float f; unsigned u; } v; v.f = f;
    return (unsigned short)((v.u + 0x7FFFu + ((v.u >> 16) & 1u)) >> 16);   // RNE
}
__device__ __forceinline__ float bfhi(unsigned w) { return __uint_as_float(w & 0xFFFF0000u); }
__device__ __forceinline__ float bflo(unsigned w) { return __uint_as_float(w << 16); }

// ---------------- Kernel 0: combined W in bf16 (row-major [128][64]) ----------------
__global__ __launch_bounds__(256) void prep_kernel(const float* __restrict__ W,
                                                   unsigned short* __restrict__ Wg) {
    const int i = blockIdx.x * 256 + threadIdx.x;   // 8192 elems
    const int j = i >> 6, d = i & 63;
    const float v = (j < 64) ? W[j * 128 + d]
                             : (W[(j - 64) * 128 + 64 + d] - W[(j - 64) * 128 + d]);
    Wg[i] = f2bf(v);
}

// ---------------- Kernel 1: projections via MFMA (LDS-staged W; R6 structure) --------
__global__ __launch_bounds__(256) void proj_kernel(const float* __restrict__ x,
                                                   const unsigned short* __restrict__ Wg,
                                                   unsigned short* __restrict__ Y1,
                                                   unsigned short* __restrict__ Bs) {
    __shared__ unsigned short Wl[128 * 72];   // row stride 144B; 2-way bank alias = free
    const int t = threadIdx.x;

    for (int i = t; i < 1024; i += 256) {     // stage 16KB Wg, coalesced dwordx4
        u4 v = ((const u4*)Wg)[i];
        *((u4*)((char*)Wl + (i >> 3) * 144 + (i & 7) * 16)) = v;
    }
    __syncthreads();

    const int lane = t & 63;
    const int wv = t >> 6;
    const int m = lane & 15;
    const int q = lane >> 4;
    const int pbase = blockIdx.x * 64 + wv * 16;

    const float* xr = x + (size_t)(pbase + m) * 64 + q * 8;
    f4 x0 = *(const f4*)(xr);
    f4 x1 = *(const f4*)(xr + 4);
    f4 x2 = *(const f4*)(xr + 32);
    f4 x3 = *(const f4*)(xr + 36);
    s8 X0, X1;
    X0[0]=(short)f2bf(x0.x); X0[1]=(short)f2bf(x0.y); X0[2]=(short)f2bf(x0.z); X0[3]=(short)f2bf(x0.w);
    X0[4]=(short)f2bf(x1.x); X0[5]=(short)f2bf(x1.y); X0[6]=(short)f2bf(x1.z); X0[7]=(short)f2bf(x1.w);
    X1[0]=(short)f2bf(x2.x); X1[1]=(short)f2bf(x2.y); X1[2]=(short)f2bf(x2.z); X1[3]=(short)f2bf(x2.w);
    X1[4]=(short)f2bf(x3.x); X1[5]=(short)f2bf(x3.y); X1[6]=(short)f2bf(x3.z); X1[7]=(short)f2bf(x3.w);

    f4 acc[8];
#pragma unroll
    for (int tt = 0; tt < 8; ++tt) acc[tt] = (f4)0.f;
#pragma unroll
    for (int s = 0; s < 2; ++s) {
        const s8 X = s ? X1 : X0;
#pragma unroll
        for (int tt = 0; tt < 8; ++tt) {
            s8 wf = *(const s8*)((const char*)Wl + (16 * tt + m) * 144 + s * 64 + q * 16);
            acc[tt] = __builtin_amdgcn_mfma_f32_16x16x32_bf16(wf, X, acc[tt], 0, 0, 0);
        }
    }

    const size_t prow = (size_t)(pbase + m) * 64;
#pragma unroll
    for (int tt = 0; tt < 4; ++tt) {
        us4 u;
        u.x = f2bf(acc[tt][0]); u.y = f2bf(acc[tt][1]);
        u.z = f2bf(acc[tt][2]); u.w = f2bf(acc[tt][3]);
        *(us4*)&Y1[prow + tt * 16 + q * 4] = u;
    }
#pragma unroll
    for (int tt = 4; tt < 8; ++tt) {
        us4 u;
        u.x = f2bf(acc[tt][0]); u.y = f2bf(acc[tt][1]);
        u.z = f2bf(acc[tt][2]); u.w = f2bf(acc[tt][3]);
        *(us4*)&Bs[prow + (tt - 4) * 16 + q * 4] = u;
    }
}

// ---------------- gather tile body: 32 points, 256 threads ----------------
__device__ __forceinline__ void gather_tile(int tile,
                                            const unsigned short* __restrict__ Y1,
                                            const unsigned short* __restrict__ Bs,
                                            const int* __restrict__ ind,
                                            const float* __restrict__ gamma,
                                            const float* __restrict__ beta,
                                            float* __restrict__ out) {
    const int lane = threadIdx.x & 63;
    const int wave = threadIdx.x >> 6;
    const int sub = lane & 7;            // channel group (8 ch)
    const int q = lane >> 3;             // point within wave
    const int bt = tile >> 8;            // 256 tiles per batch
    const int jj = tile & 255;
    const int p = bt * N_ + jj * 32 + wave * 8 + q;
    const int bbase = bt * N_ * 64;

    int idxs[K_];
    const int4* ip = (const int4*)&ind[p * K_];   // 80B/point, 16B-aligned
#pragma unroll
    for (int v = 0; v < 5; ++v) {
        int4 iv = ip[v];
        idxs[4 * v + 0] = iv.x; idxs[4 * v + 1] = iv.y;
        idxs[4 * v + 2] = iv.z; idxs[4 * v + 3] = iv.w;
    }

    f4 ma = (f4)(-INFINITY), mb = (f4)(-INFINITY);
#pragma unroll
    for (int r = 0; r < 2; ++r) {        // 2 rounds x 10 outstanding 16B gathers
        u4 rv[10];
#pragma unroll
        for (int k = 0; k < 10; ++k)
            rv[k] = *(const u4*)(Y1 + bbase + idxs[r * 10 + k] * 64 + sub * 8);
#pragma unroll
        for (int k = 0; k < 10; ++k) {
            ma.x = fmaxf(ma.x, bflo(rv[k].x)); ma.y = fmaxf(ma.y, bfhi(rv[k].x));
            ma.z = fmaxf(ma.z, bflo(rv[k].y)); ma.w = fmaxf(ma.w, bfhi(rv[k].y));
            mb.x = fmaxf(mb.x, bflo(rv[k].z)); mb.y = fmaxf(mb.y, bfhi(rv[k].z));
            mb.z = fmaxf(mb.z, bflo(rv[k].w)); mb.w = fmaxf(mb.w, bfhi(rv[k].w));
        }
    }

    u4 bsv = __builtin_nontemporal_load((const u4*)(Bs + (size_t)p * 64 + sub * 8));
    f4 ha, hb;
    ha.x = ma.x + bflo(bsv.x); ha.y = ma.y + bfhi(bsv.x);
    ha.z = ma.z + bflo(bsv.y); ha.w = ma.w + bfhi(bsv.y);
    hb.x = mb.x + bflo(bsv.z); hb.y = mb.y + bfhi(bsv.z);
    hb.z = mb.z + bflo(bsv.w); hb.w = mb.w + bfhi(bsv.w);

    float s = ha.x + ha.y + ha.z + ha.w + hb.x + hb.y + hb.z + hb.w;
#pragma unroll
    for (int off = 4; off >= 1; off >>= 1) s += __shfl_xor(s, off, 64);
    const float mu = s * (1.0f / 64.0f);
    f4 da = ha - mu, db = hb - mu;
    float v2 = da.x * da.x + da.y * da.y + da.z * da.z + da.w * da.w
             + db.x * db.x + db.y * db.y + db.z * db.z + db.w * db.w;
#pragma unroll
    for (int off = 4; off >= 1; off >>= 1) v2 += __shfl_xor(v2, off, 64);
    const float rstd = rsqrtf(v2 * (1.0f / 64.0f) + 1e-5f);

    const f4 g0 = *(const f4*)&gamma[sub * 8];
    const f4 g1 = *(const f4*)&gamma[sub * 8 + 4];
    const f4 b0 = *(const f4*)&beta[sub * 8];
    const f4 b1 = *(const f4*)&beta[sub * 8 + 4];
    f4 na = da * rstd * g0 + b0;
    f4 nb = db * rstd * g1 + b1;

    f4 r0, r1;
    r0.x = 0.5f * na.x * (1.0f + erff(na.x * 0.70710678f));
    r0.y = 0.5f * na.y * (1.0f + erff(na.y * 0.70710678f));
    r0.z = 0.5f * na.z * (1.0f + erff(na.z * 0.70710678f));
    r0.w = 0.5f * na.w * (1.0f + erff(na.w * 0.70710678f));
    r1.x = 0.5f * nb.x * (1.0f + erff(nb.x * 0.70710678f));
    r1.y = 0.5f * nb.y * (1.0f + erff(nb.y * 0.70710678f));
    r1.z = 0.5f * nb.z * (1.0f + erff(nb.z * 0.70710678f));
    r1.w = 0.5f * nb.w * (1.0f + erff(nb.w * 0.70710678f));
    float* op = &out[(size_t)p * 64 + sub * 8];
    __builtin_nontemporal_store(r0, (f4*)op);
    __builtin_nontemporal_store(r1, (f4*)(op + 4));
}

// ---------------- Kernel 2: gather with dynamic XCD-affine tile claiming ----------------
// Block reads its physical XCD id (HW_REG_XCC_ID=20, gfx940+) and claims tiles from its
// XCD's group (batches {2g,2g+1}) via ticket+CAS. Fallback: global ticket sweep over all
// tiles guarantees completeness regardless of block->XCD distribution (2x oversubscribed).
#define HWREG_XCC_ID_IMM (20 | (31 << 11))   // id=20, offset=0, size=32

__global__ __launch_bounds__(256) void gather_kernel(const unsigned short* __restrict__ Y1,
                                                     const unsigned short* __restrict__ Bs,
                                                     const int* __restrict__ ind,
                                                     const float* __restrict__ gamma,
                                                     const float* __restrict__ beta,
                                                     float* __restrict__ out,
                                                     unsigned* __restrict__ cnt,    // [8] group tickets
                                                     unsigned* __restrict__ cntg,   // [1] global ticket
                                                     unsigned* __restrict__ flags)  // [NTILE] claims
{
    __shared__ int tile_s;
    const int g = (int)(__builtin_amdgcn_s_getreg(HWREG_XCC_ID_IMM) & 7u);

    for (;;) {
        if (threadIdx.x == 0) {
            int tile = -1;
            // local phase: tiles of this XCD's group
            for (;;) {
                unsigned t = atomicAdd(&cnt[g], 1u);
                if (t >= TPG) break;
                int cand = g * TPG + (int)t;
                if (atomicCAS(&flags[cand], 0u, 1u) == 0u) { tile = cand; break; }
            }
            // fallback: global sweep (completeness net)
            if (tile < 0) {
                for (;;) {
                    unsigned t = atomicAdd(cntg, 1u);
                    if (t >= NTILE) break;
                    if (atomicCAS(&flags[t], 0u, 1u) == 0u) { tile = (int)t; break; }
                }
            }
            tile_s = tile;
        }
        __syncthreads();
        const int tile = tile_s;
        __syncthreads();
        if (tile < 0) return;
        gather_tile(tile, Y1, Bs, ind, gamma, beta, out);
        return;   // one tile per block (8192 blocks >= 4096 tiles)
    }
}

extern "C" void kernel_launch(void* const* d_in, const int* in_sizes, int n_in,
                              void* d_out, int out_size, void* d_ws, size_t ws_size,
                              hipStream_t stream) {
    const float* x     = (const float*)d_in[0];
    const int*   ind   = (const int*)d_in[1];
    const float* W     = (const float*)d_in[2];
    const float* gamma = (const float*)d_in[3];
    const float* beta  = (const float*)d_in[4];
    float* out = (float*)d_out;

    unsigned short* Bs = (unsigned short*)d_ws;          // 16.8 MB bf16
    unsigned short* Y1 = Bs + (size_t)NPTS * 64;         // 16.8 MB bf16
    unsigned short* Wg = Y1 + (size_t)NPTS * 64;         // 16 KB bf16
    unsigned* sched = (unsigned*)(Wg + 8192);            // cnt[8] + cntg[1] + pad + flags[4096]
    unsigned* cnt   = sched;
    unsigned* cntg  = sched + 8;
    unsigned* flags = sched + 16;

    hipMemsetAsync(sched, 0, (16 + NTILE) * sizeof(unsigned), stream);
    prep_kernel<<<32, 256, 0, stream>>>(W, Wg);
    proj_kernel<<<NPTS / 64, 256, 0, stream>>>(x, Wg, Y1, Bs);
    gather_kernel<<<2 * NTILE, 256, 0, stream>>>(Y1, Bs, ind, gamma, beta, out,
                                                 cnt, cntg, flags);
}